// Round 1
// baseline (662.266 us; speedup 1.0000x reference)
//
#include <hip/hip_runtime.h>
#include <hip/hip_bf16.h>
#include <stdint.h>

// B=4, T=2048, C=1024, H=16, HD=64
#define B_  4
#define T_  2048
#define C_  1024
#define H_  16
#define HD_ 64
#define YSZ 8388608  // B*T*C

typedef __attribute__((ext_vector_type(8))) __bf16 bf16x8;
typedef __attribute__((ext_vector_type(4))) float  f32x4;

__device__ __forceinline__ ushort f2bf(float x) {
  union { float f; uint32_t u; } v; v.f = x;
  uint32_t r = v.u + 0x7FFFu + ((v.u >> 16) & 1u);
  return (ushort)(r >> 16);
}

__device__ __forceinline__ void async16(void* lds, const void* g) {
  __builtin_amdgcn_global_load_lds(
      (const __attribute__((address_space(1))) void*)g,
      (__attribute__((address_space(3))) void*)lds, 16, 0, 0);
}

// ---------------- prep: fp32 -> bf16 (vectorized) ----------------
__global__ __launch_bounds__(256) void k_cvt(const float* __restrict__ in,
                                             ushort* __restrict__ out, int n4) {
  int i = blockIdx.x * 256 + threadIdx.x;
  if (i < n4) {
    const float4 v = ((const float4*)in)[i];
    ushort4 o; o.x = f2bf(v.x); o.y = f2bf(v.y); o.z = f2bf(v.z); o.w = f2bf(v.w);
    ((ushort4*)out)[i] = o;
  }
}

// ---------------- prep: transpose fp32 [rows][cols] -> bf16 [cols][rows] ----
__global__ __launch_bounds__(256) void k_transpose_bf16(const float* __restrict__ in,
                                                        ushort* __restrict__ out,
                                                        int rows, int cols) {
  __shared__ float tile[32][33];
  const int bx = blockIdx.x * 32;  // col base
  const int by = blockIdx.y * 32;  // row base
  const int tx = threadIdx.x & 31;
  const int ty = threadIdx.x >> 5;  // 0..7
#pragma unroll
  for (int j = 0; j < 4; ++j)
    tile[ty + j * 8][tx] = in[(size_t)(by + ty + j * 8) * cols + bx + tx];
  __syncthreads();
#pragma unroll
  for (int j = 0; j < 4; ++j)
    out[(size_t)(bx + ty + j * 8) * rows + by + tx] = f2bf(tile[tx][ty + j * 8]);
}

// ---------------- bf16 MFMA GEMM, 128x128 tile, BK=64 ----------------
// A [M][K] bf16 row-major, Bt [N][K] bf16 row-major (i.e. B transposed).
// MODE 0: QKV epilogue (bias + pos_emb, head-split, k/v fp32 out, q/k bf16, v^T bf16)
// MODE 1: proj epilogue (bias, fp32 y out)
template <int MODE>
__global__ __launch_bounds__(256) void k_gemm(
    const ushort* __restrict__ A, const ushort* __restrict__ Bt,
    const float* __restrict__ bias, const float* __restrict__ pos,
    float* __restrict__ outY, ushort* __restrict__ qbf, ushort* __restrict__ kbf,
    ushort* __restrict__ vtbf, int M, int N, int K) {
  __shared__ ushort Ab[128 * 64];
  __shared__ ushort Bb[128 * 64];
  const int tid = threadIdx.x;
  const int wid = tid >> 6, lane = tid & 63;
  const int wr = wid >> 1, wc = wid & 1;
  const int g = lane >> 4, c = lane & 15;
  const int bm = blockIdx.x * 128;
  const int bn = blockIdx.y * 128;

  f32x4 acc[4][4] = {};

  const int r0 = wid * 8 + (lane >> 3);  // row-in-round
  const int ch = lane & 7;               // 16B chunk within 128B row

  for (int kt = 0; kt < K; kt += 64) {
    __syncthreads();
#pragma unroll
    for (int rnd = 0; rnd < 4; ++rnd) {
      const int r = rnd * 32 + r0;
      const int gc = (ch ^ (r & 7)) << 3;  // pre-swizzled global col (elements)
      async16((char*)Ab + rnd * 4096 + wid * 1024,
              A + (size_t)(bm + r) * K + kt + gc);
      async16((char*)Bb + rnd * 4096 + wid * 1024,
              Bt + (size_t)(bn + r) * K + kt + gc);
    }
    __syncthreads();
#pragma unroll
    for (int ks = 0; ks < 2; ++ks) {
      bf16x8 af[4], bfr[4];
#pragma unroll
      for (int m = 0; m < 4; ++m) {
        const int row = wr * 64 + m * 16 + c;
        const int bir = (ks * 64 + g * 16) ^ ((row & 7) << 4);
        af[m] = *(const bf16x8*)((const char*)Ab + row * 128 + bir);
      }
#pragma unroll
      for (int n = 0; n < 4; ++n) {
        const int row = wc * 64 + n * 16 + c;
        const int bir = (ks * 64 + g * 16) ^ ((row & 7) << 4);
        bfr[n] = *(const bf16x8*)((const char*)Bb + row * 128 + bir);
      }
#pragma unroll
      for (int m = 0; m < 4; ++m)
#pragma unroll
        for (int n = 0; n < 4; ++n)
          acc[m][n] = __builtin_amdgcn_mfma_f32_16x16x32_bf16(af[m], bfr[n],
                                                              acc[m][n], 0, 0, 0);
    }
  }

  // epilogue: D row=(lane>>4)*4+j, col=lane&15 (measured layout)
#pragma unroll
  for (int m = 0; m < 4; ++m) {
    const int rowbase = bm + wr * 64 + m * 16 + g * 4;
#pragma unroll
    for (int n = 0; n < 4; ++n) {
      const int col = bn + wc * 64 + n * 16 + c;
#pragma unroll
      for (int j = 0; j < 4; ++j) {
        const int i = rowbase + j;
        float val = acc[m][n][j] + bias[col];
        if (MODE == 1) {
          outY[(size_t)i * N + col] = val;
        } else {
          const int b = i >> 11, t = i & 2047;
          if (col < C_) {  // q
            val += pos[t * C_ + col];
            const int h = col >> 6, hd = col & 63;
            const size_t o = (((size_t)(b * H_ + h)) * T_ + t) * HD_ + hd;
            qbf[o] = f2bf(val);
          } else if (col < 2 * C_) {  // k
            const int cc = col - C_;
            val += pos[t * C_ + cc];
            const int h = cc >> 6, hd = cc & 63;
            const size_t o = (((size_t)(b * H_ + h)) * T_ + t) * HD_ + hd;
            outY[(size_t)YSZ + o] = val;
            kbf[o] = f2bf(val);
          } else {  // v
            const int cc = col - 2 * C_;
            const int h = cc >> 6, hd = cc & 63;
            const size_t o = (((size_t)(b * H_ + h)) * T_ + t) * HD_ + hd;
            outY[(size_t)(2 * YSZ) + o] = val;
            vtbf[(((size_t)(b * H_ + h)) * HD_ + hd) * T_ + t] = f2bf(val);
          }
        }
      }
    }
  }
}

// ---------------- flash attention, bf16 MFMA, online softmax ----------------
// q,k: [BH][T][64] bf16 ; vT: [BH][64][T] bf16 ; yatt out: [B*T][C] bf16
__global__ __launch_bounds__(256) void k_attn(const ushort* __restrict__ qbf,
                                              const ushort* __restrict__ kbf,
                                              const ushort* __restrict__ vtbf,
                                              ushort* __restrict__ yatt) {
  __shared__ ushort Kb[64 * 64];
  __shared__ ushort Vb[64 * 64];
  __shared__ ushort Pb[4][2048];  // per-wave 32x64 bf16
  const int tid = threadIdx.x;
  const int wid = tid >> 6, lane = tid & 63;
  const int g = lane >> 4, c = lane & 15;
  const int qbase = blockIdx.x * 128;
  const int bh = blockIdx.y;
  const size_t bhT = (size_t)bh * T_ * 64;

  // Q fragments in registers (rows qbase+wid*32+m*16+c, k = ks*32+g*8)
  bf16x8 qf[2][2];
#pragma unroll
  for (int m = 0; m < 2; ++m)
#pragma unroll
    for (int ks = 0; ks < 2; ++ks)
      qf[m][ks] = *(const bf16x8*)(qbf + bhT +
                                   (size_t)(qbase + wid * 32 + m * 16 + c) * 64 +
                                   ks * 32 + g * 8);

  f32x4 o[2][4] = {};
  float mrow[2][4], lrow[2][4];
#pragma unroll
  for (int m = 0; m < 2; ++m)
#pragma unroll
    for (int j = 0; j < 4; ++j) { mrow[m][j] = -__builtin_inff(); lrow[m][j] = 0.f; }

  const int r0 = wid * 8 + (lane >> 3);
  const int ch = lane & 7;
  const int ntiles = qbase / 64 + 2;
  const float SC = 0.125f * 1.4426950408889634f;  // 1/sqrt(64) * log2(e)
  const int qmin = qbase + wid * 32;

  for (int t = 0; t < ntiles; ++t) {
    const int kv0 = t * 64;
    __syncthreads();
#pragma unroll
    for (int rnd = 0; rnd < 2; ++rnd) {
      const int r = rnd * 32 + r0;
      const int gc = (ch ^ (r & 7)) << 3;
      async16((char*)Kb + rnd * 4096 + wid * 1024,
              kbf + bhT + (size_t)(kv0 + r) * 64 + gc);
      async16((char*)Vb + rnd * 4096 + wid * 1024,
              vtbf + bhT + (size_t)r * T_ + kv0 + gc);
    }
    __syncthreads();

    // S = q k^T  (D: row=q=g*4+j+m*16, col=kv=n*16+c)
    f32x4 s[2][4] = {};
#pragma unroll
    for (int ks = 0; ks < 2; ++ks) {
      bf16x8 kf[4];
#pragma unroll
      for (int n = 0; n < 4; ++n) {
        const int row = n * 16 + c;
        const int bir = (ks * 64 + g * 16) ^ ((row & 7) << 4);
        kf[n] = *(const bf16x8*)((const char*)Kb + row * 128 + bir);
      }
#pragma unroll
      for (int m = 0; m < 2; ++m)
#pragma unroll
        for (int n = 0; n < 4; ++n)
          s[m][n] = __builtin_amdgcn_mfma_f32_16x16x32_bf16(qf[m][ks], kf[n],
                                                            s[m][n], 0, 0, 0);
    }

    // scale + causal mask
    const bool needmask = (kv0 + 63 > qmin);
#pragma unroll
    for (int m = 0; m < 2; ++m)
#pragma unroll
      for (int n = 0; n < 4; ++n)
#pragma unroll
        for (int j = 0; j < 4; ++j) {
          float v = s[m][n][j] * SC;
          if (needmask) {
            const int kvi = kv0 + n * 16 + c;
            const int qi = qbase + wid * 32 + m * 16 + g * 4 + j;
            if (kvi > qi) v = -__builtin_inff();
          }
          s[m][n][j] = v;
        }

    // online softmax per row (row lives in one 16-lane group -> shfl_xor 1,2,4,8)
#pragma unroll
    for (int m = 0; m < 2; ++m)
#pragma unroll
      for (int j = 0; j < 4; ++j) {
        float mx = s[m][0][j];
#pragma unroll
        for (int n = 1; n < 4; ++n) mx = fmaxf(mx, s[m][n][j]);
#pragma unroll
        for (int w = 1; w < 16; w <<= 1) mx = fmaxf(mx, __shfl_xor(mx, w));
        const float mnew = fmaxf(mrow[m][j], mx);
        const float corr = exp2f(mrow[m][j] - mnew);
        float rs = 0.f;
#pragma unroll
        for (int n = 0; n < 4; ++n) {
          const float pv = exp2f(s[m][n][j] - mnew);
          s[m][n][j] = pv;
          rs += pv;
        }
#pragma unroll
        for (int w = 1; w < 16; w <<= 1) rs += __shfl_xor(rs, w);
        lrow[m][j] = lrow[m][j] * corr + rs;
        mrow[m][j] = mnew;
#pragma unroll
        for (int n = 0; n < 4; ++n) o[m][n][j] *= corr;
      }

    // P -> per-wave LDS (swizzled [32 q][64 kv] bf16), then PV
    asm volatile("" ::: "memory");
    char* pb = (char*)&Pb[wid][0];
#pragma unroll
    for (int m = 0; m < 2; ++m)
#pragma unroll
      for (int n = 0; n < 4; ++n)
#pragma unroll
        for (int j = 0; j < 4; ++j) {
          const int row = m * 16 + g * 4 + j;
          const int byte = row * 128 + ((((n * 16 + c) * 2)) ^ ((row & 7) << 4));
          *(ushort*)(pb + byte) = f2bf(s[m][n][j]);
        }
    asm volatile("" ::: "memory");

#pragma unroll
    for (int ks = 0; ks < 2; ++ks) {
      bf16x8 pf[2], vf[4];
#pragma unroll
      for (int m = 0; m < 2; ++m) {
        const int row = m * 16 + c;
        const int bir = (ks * 64 + g * 16) ^ ((row & 7) << 4);
        pf[m] = *(const bf16x8*)(pb + row * 128 + bir);
      }
#pragma unroll
      for (int n = 0; n < 4; ++n) {
        const int row = n * 16 + c;
        const int bir = (ks * 64 + g * 16) ^ ((row & 7) << 4);
        vf[n] = *(const bf16x8*)((const char*)Vb + row * 128 + bir);
      }
#pragma unroll
      for (int m = 0; m < 2; ++m)
#pragma unroll
        for (int n = 0; n < 4; ++n)
          o[m][n] = __builtin_amdgcn_mfma_f32_16x16x32_bf16(pf[m], vf[n],
                                                            o[m][n], 0, 0, 0);
    }
  }

  // finalize y = o/l, write merged [B*T][C] bf16
  const int b = bh >> 4, h = bh & 15;
#pragma unroll
  for (int m = 0; m < 2; ++m)
#pragma unroll
    for (int j = 0; j < 4; ++j) {
      const float inv = 1.0f / lrow[m][j];
      const int qi = qbase + wid * 32 + m * 16 + g * 4 + j;
      const size_t rowoff = ((size_t)b * T_ + qi) * C_ + h * 64;
#pragma unroll
      for (int n = 0; n < 4; ++n)
        yatt[rowoff + n * 16 + c] = f2bf(o[m][n][j] * inv);
    }
}

// ---------------- launch ----------------
extern "C" void kernel_launch(void* const* d_in, const int* in_sizes, int n_in,
                              void* d_out, int out_size, void* d_ws, size_t ws_size,
                              hipStream_t stream) {
  (void)in_sizes; (void)n_in; (void)out_size;
  const float* x      = (const float*)d_in[0];
  const float* pos    = (const float*)d_in[1];
  const float* w_attn = (const float*)d_in[2];
  const float* b_attn = (const float*)d_in[3];
  const float* w_proj = (const float*)d_in[4];
  const float* b_proj = (const float*)d_in[5];
  float* out = (float*)d_out;

  if (ws_size < (size_t)(88u << 20)) return;  // need 88MB scratch
  char* ws = (char*)d_ws;
  ushort* xbf  = (ushort*)(ws);                       // 16MB  x bf16 [8192][1024]
  ushort* waT  = (ushort*)(ws + (16 << 20));          // 6MB   w_attn^T bf16 [3072][1024]
  ushort* wpT  = (ushort*)(ws + (22 << 20));          // 2MB   w_proj^T bf16 [1024][1024]
  ushort* qbf  = (ushort*)(ws + (24 << 20));          // 16MB  q bf16 [BH][T][64]
  ushort* kbf  = (ushort*)(ws + (40 << 20));          // 16MB  k bf16 [BH][T][64]
  ushort* vtbf = (ushort*)(ws + (56 << 20));          // 16MB  v^T bf16 [BH][64][T]
  ushort* yatt = (ushort*)(ws + (72 << 20));          // 16MB  attn out bf16 [8192][1024]

  k_cvt<<<8192, 256, 0, stream>>>(x, xbf, 2097152);
  k_transpose_bf16<<<dim3(96, 32), 256, 0, stream>>>(w_attn, waT, 1024, 3072);
  k_transpose_bf16<<<dim3(32, 32), 256, 0, stream>>>(w_proj, wpT, 1024, 1024);
  k_gemm<0><<<dim3(64, 24), 256, 0, stream>>>(xbf, waT, b_attn, pos, out, qbf, kbf,
                                              vtbf, 8192, 3072, 1024);
  k_attn<<<dim3(16, 64), 256, 0, stream>>>(qbf, kbf, vtbf, yatt);
  k_gemm<1><<<dim3(64, 8), 256, 0, stream>>>(yatt, wpT, b_proj, nullptr, out, nullptr,
                                             nullptr, nullptr, 8192, 1024, 1024);
}

// Round 3
// 429.834 us; speedup vs baseline: 1.5407x; 1.5407x over previous
//
#include <hip/hip_runtime.h>
#include <hip/hip_bf16.h>
#include <stdint.h>

// B=4, T=2048, C=1024, H=16, HD=64
#define B_  4
#define T_  2048
#define C_  1024
#define H_  16
#define HD_ 64
#define YSZ 8388608  // B*T*C

typedef __attribute__((ext_vector_type(8))) __bf16 bf16x8;
typedef __attribute__((ext_vector_type(4))) float  f32x4;

__device__ __forceinline__ ushort f2bf(float x) {
  union { float f; uint32_t u; } v; v.f = x;
  uint32_t r = v.u + 0x7FFFu + ((v.u >> 16) & 1u);
  return (ushort)(r >> 16);
}

__device__ __forceinline__ void async16(void* lds, const void* g) {
  __builtin_amdgcn_global_load_lds(
      (const __attribute__((address_space(1))) void*)g,
      (__attribute__((address_space(3))) void*)lds, 16, 0, 0);
}

// ---------------- prep: fp32 -> bf16 (vectorized) ----------------
__global__ __launch_bounds__(256) void k_cvt(const float* __restrict__ in,
                                             ushort* __restrict__ out, int n4) {
  int i = blockIdx.x * 256 + threadIdx.x;
  if (i < n4) {
    const float4 v = ((const float4*)in)[i];
    ushort4 o; o.x = f2bf(v.x); o.y = f2bf(v.y); o.z = f2bf(v.z); o.w = f2bf(v.w);
    ((ushort4*)out)[i] = o;
  }
}

// ---------------- prep: transpose fp32 [rows][cols] -> bf16 [cols][rows] ----
__global__ __launch_bounds__(256) void k_transpose_bf16(const float* __restrict__ in,
                                                        ushort* __restrict__ out,
                                                        int rows, int cols) {
  __shared__ float tile[32][33];
  const int bx = blockIdx.x * 32;  // col base
  const int by = blockIdx.y * 32;  // row base
  const int tx = threadIdx.x & 31;
  const int ty = threadIdx.x >> 5;  // 0..7
#pragma unroll
  for (int j = 0; j < 4; ++j)
    tile[ty + j * 8][tx] = in[(size_t)(by + ty + j * 8) * cols + bx + tx];
  __syncthreads();
#pragma unroll
  for (int j = 0; j < 4; ++j)
    out[(size_t)(bx + ty + j * 8) * rows + by + tx] = f2bf(tile[tx][ty + j * 8]);
}

// ---------------- bf16 MFMA GEMM, 128x128 tile, BK=64 ----------------
// A [M][K] bf16 row-major, Bt [N][K] bf16 row-major (i.e. B transposed).
// MODE 0: QKV epilogue (bias + pos_emb, head-split, k/v fp32 out, q/k bf16, v^T bf16)
//         q is pre-scaled by 1/sqrt(HD)*log2(e) for the attn exp2 domain.
// MODE 1: proj epilogue (bias, fp32 y out)
template <int MODE>
__global__ __launch_bounds__(256) void k_gemm(
    const ushort* __restrict__ A, const ushort* __restrict__ Bt,
    const float* __restrict__ bias, const float* __restrict__ pos,
    float* __restrict__ outY, ushort* __restrict__ qbf, ushort* __restrict__ kbf,
    ushort* __restrict__ vtbf, int M, int N, int K) {
  __shared__ ushort Ab[128 * 64];
  __shared__ ushort Bb[128 * 64];
  const int tid = threadIdx.x;
  const int wid = tid >> 6, lane = tid & 63;
  const int wr = wid >> 1, wc = wid & 1;
  const int g = lane >> 4, c = lane & 15;
  const int bm = blockIdx.x * 128;
  const int bn = blockIdx.y * 128;

  f32x4 acc[4][4] = {};

  const int r0 = wid * 8 + (lane >> 3);  // row-in-round
  const int ch = lane & 7;               // 16B chunk within 128B row

  for (int kt = 0; kt < K; kt += 64) {
    __syncthreads();
#pragma unroll
    for (int rnd = 0; rnd < 4; ++rnd) {
      const int r = rnd * 32 + r0;
      const int gc = (ch ^ (r & 7)) << 3;  // pre-swizzled global col (elements)
      async16((char*)Ab + rnd * 4096 + wid * 1024,
              A + (size_t)(bm + r) * K + kt + gc);
      async16((char*)Bb + rnd * 4096 + wid * 1024,
              Bt + (size_t)(bn + r) * K + kt + gc);
    }
    __syncthreads();
#pragma unroll
    for (int ks = 0; ks < 2; ++ks) {
      bf16x8 af[4], bfr[4];
#pragma unroll
      for (int m = 0; m < 4; ++m) {
        const int row = wr * 64 + m * 16 + c;
        const int bir = (ks * 64 + g * 16) ^ ((row & 7) << 4);
        af[m] = *(const bf16x8*)((const char*)Ab + row * 128 + bir);
      }
#pragma unroll
      for (int n = 0; n < 4; ++n) {
        const int row = wc * 64 + n * 16 + c;
        const int bir = (ks * 64 + g * 16) ^ ((row & 7) << 4);
        bfr[n] = *(const bf16x8*)((const char*)Bb + row * 128 + bir);
      }
#pragma unroll
      for (int m = 0; m < 4; ++m)
#pragma unroll
        for (int n = 0; n < 4; ++n)
          acc[m][n] = __builtin_amdgcn_mfma_f32_16x16x32_bf16(af[m], bfr[n],
                                                              acc[m][n], 0, 0, 0);
    }
  }

  // epilogue: D row=(lane>>4)*4+j, col=lane&15 (measured layout)
  const float QSC = 0.125f * 1.4426950408889634f;  // 1/sqrt(64) * log2(e)
#pragma unroll
  for (int m = 0; m < 4; ++m) {
    const int rowbase = bm + wr * 64 + m * 16 + g * 4;
#pragma unroll
    for (int n = 0; n < 4; ++n) {
      const int col = bn + wc * 64 + n * 16 + c;
#pragma unroll
      for (int j = 0; j < 4; ++j) {
        const int i = rowbase + j;
        float val = acc[m][n][j] + bias[col];
        if (MODE == 1) {
          outY[(size_t)i * N + col] = val;
        } else {
          const int b = i >> 11, t = i & 2047;
          if (col < C_) {  // q (pre-scaled for attn)
            val += pos[t * C_ + col];
            const int h = col >> 6, hd = col & 63;
            const size_t o = (((size_t)(b * H_ + h)) * T_ + t) * HD_ + hd;
            qbf[o] = f2bf(val * QSC);
          } else if (col < 2 * C_) {  // k
            const int cc = col - C_;
            val += pos[t * C_ + cc];
            const int h = cc >> 6, hd = cc & 63;
            const size_t o = (((size_t)(b * H_ + h)) * T_ + t) * HD_ + hd;
            outY[(size_t)YSZ + o] = val;
            kbf[o] = f2bf(val);
          } else {  // v
            const int cc = col - 2 * C_;
            const int h = cc >> 6, hd = cc & 63;
            const size_t o = (((size_t)(b * H_ + h)) * T_ + t) * HD_ + hd;
            outY[(size_t)(2 * YSZ) + o] = val;
            vtbf[(((size_t)(b * H_ + h)) * HD_ + hd) * T_ + t] = f2bf(val);
          }
        }
      }
    }
  }
}

// ---------------- flash attention, bf16 MFMA, online softmax ----------------
// q,k: [BH][T][64] bf16 (q pre-scaled) ; vT: [BH][64][T] bf16 ;
// yatt out: [B*T][C] bf16.
// Balanced causal pairing: block blockIdx.x handles q-tiles (x, 15-x), each
// 128 rows -> every block does exactly 34 KV tiles of work.
// K/V staging double-buffered: stage(t+1) issued before compute(t); the
// single per-tile barrier drains the prefetch after a full compute phase.
__global__ __launch_bounds__(256) void k_attn(const ushort* __restrict__ qbf,
                                              const ushort* __restrict__ kbf,
                                              const ushort* __restrict__ vtbf,
                                              ushort* __restrict__ yatt) {
  __shared__ ushort Kb[2][64 * 64];
  __shared__ ushort Vb[2][64 * 64];
  __shared__ ushort Pb[4][2048];  // per-wave 32x64 bf16
  const int tid = threadIdx.x;
  const int wid = tid >> 6, lane = tid & 63;
  const int g = lane >> 4, c = lane & 15;
  const int bh = blockIdx.y;
  const size_t bhT = (size_t)bh * T_ * 64;
  const int r0 = wid * 8 + (lane >> 3);
  const int ch = lane & 7;
  const int b = bh >> 4, h = bh & 15;

  auto stage = [&](int buf, int t) {
    const int kv0 = t * 64;
#pragma unroll
    for (int rnd = 0; rnd < 2; ++rnd) {
      const int r = rnd * 32 + r0;
      const int gc = (ch ^ (r & 7)) << 3;
      async16((char*)Kb[buf] + rnd * 4096 + wid * 1024,
              kbf + bhT + (size_t)(kv0 + r) * 64 + gc);
      async16((char*)Vb[buf] + rnd * 4096 + wid * 1024,
              vtbf + bhT + (size_t)r * T_ + kv0 + gc);
    }
  };

  for (int half = 0; half < 2; ++half) {
    const int qtile = half ? (15 - (int)blockIdx.x) : (int)blockIdx.x;
    const int qbase = qtile * 128;
    const int ntiles = qtile * 2 + 2;
    const int qmin = qbase + wid * 32;

    // Q fragments in registers (rows qbase+wid*32+m*16+c, k = ks*32+g*8)
    bf16x8 qf[2][2];
#pragma unroll
    for (int m = 0; m < 2; ++m)
#pragma unroll
      for (int ks = 0; ks < 2; ++ks)
        qf[m][ks] = *(const bf16x8*)(qbf + bhT +
                                     (size_t)(qbase + wid * 32 + m * 16 + c) * 64 +
                                     ks * 32 + g * 8);

    f32x4 o[2][4] = {};
    float mrow[2][4], lrow[2][4];
#pragma unroll
    for (int m = 0; m < 2; ++m)
#pragma unroll
      for (int j = 0; j < 4; ++j) { mrow[m][j] = -__builtin_inff(); lrow[m][j] = 0.f; }

    for (int t = 0; t < ntiles; ++t) {
      if (t == 0) {            // prologue: wait for prior readers, stage tile 0
        __syncthreads();
        stage(0, 0);
      }
      __syncthreads();         // compiler drains vmcnt -> buf[t&1] ready
      if (t + 1 < ntiles) stage((t + 1) & 1, t + 1);  // prefetch under compute

      const char* kb = (const char*)Kb[t & 1];
      const char* vb = (const char*)Vb[t & 1];
      const int kv0 = t * 64;

      // S = q k^T  (D: row=q=g*4+j+m*16, col=kv=n*16+c); q pre-scaled
      f32x4 s[2][4] = {};
      __builtin_amdgcn_s_setprio(1);
#pragma unroll
      for (int ks = 0; ks < 2; ++ks) {
        bf16x8 kf[4];
#pragma unroll
        for (int n = 0; n < 4; ++n) {
          const int row = n * 16 + c;
          const int bir = (ks * 64 + g * 16) ^ ((row & 7) << 4);
          kf[n] = *(const bf16x8*)(kb + row * 128 + bir);
        }
#pragma unroll
        for (int m = 0; m < 2; ++m)
#pragma unroll
          for (int n = 0; n < 4; ++n)
            s[m][n] = __builtin_amdgcn_mfma_f32_16x16x32_bf16(qf[m][ks], kf[n],
                                                              s[m][n], 0, 0, 0);
      }
      __builtin_amdgcn_s_setprio(0);

      // causal mask (only tiles overlapping this wave's q range)
      const bool needmask = (kv0 + 63 > qmin);
      if (needmask) {
#pragma unroll
        for (int m = 0; m < 2; ++m)
#pragma unroll
          for (int n = 0; n < 4; ++n) {
            const int kvi = kv0 + n * 16 + c;
#pragma unroll
            for (int j = 0; j < 4; ++j) {
              const int qi = qbase + wid * 32 + m * 16 + g * 4 + j;
              if (kvi > qi) s[m][n][j] = -__builtin_inff();
            }
          }
      }

      // online softmax per row (exp2 domain; row in one 16-lane group)
#pragma unroll
      for (int m = 0; m < 2; ++m)
#pragma unroll
        for (int j = 0; j < 4; ++j) {
          float mx = fmaxf(fmaxf(s[m][0][j], s[m][1][j]),
                           fmaxf(s[m][2][j], s[m][3][j]));
#pragma unroll
          for (int w = 1; w < 16; w <<= 1) mx = fmaxf(mx, __shfl_xor(mx, w));
          const float mnew = fmaxf(mrow[m][j], mx);
          const float corr = exp2f(mrow[m][j] - mnew);
          float rs = 0.f;
#pragma unroll
          for (int n = 0; n < 4; ++n) {
            const float pv = exp2f(s[m][n][j] - mnew);
            s[m][n][j] = pv;
            rs += pv;
          }
#pragma unroll
          for (int w = 1; w < 16; w <<= 1) rs += __shfl_xor(rs, w);
          lrow[m][j] = lrow[m][j] * corr + rs;
          mrow[m][j] = mnew;
#pragma unroll
          for (int n = 0; n < 4; ++n) o[m][n][j] *= corr;
        }

      // P -> per-wave LDS (swizzled [32 q][64 kv] bf16), then PV
      asm volatile("" ::: "memory");
      char* pb = (char*)&Pb[wid][0];
#pragma unroll
      for (int m = 0; m < 2; ++m)
#pragma unroll
        for (int n = 0; n < 4; ++n)
#pragma unroll
          for (int j = 0; j < 4; ++j) {
            const int row = m * 16 + g * 4 + j;
            const int byte = row * 128 + ((((n * 16 + c) * 2)) ^ ((row & 7) << 4));
            *(ushort*)(pb + byte) = f2bf(s[m][n][j]);
          }
      asm volatile("" ::: "memory");

      __builtin_amdgcn_s_setprio(1);
#pragma unroll
      for (int ks = 0; ks < 2; ++ks) {
        bf16x8 pf[2], vf[4];
#pragma unroll
        for (int m = 0; m < 2; ++m) {
          const int row = m * 16 + c;
          const int bir = (ks * 64 + g * 16) ^ ((row & 7) << 4);
          pf[m] = *(const bf16x8*)(pb + row * 128 + bir);
        }
#pragma unroll
        for (int n = 0; n < 4; ++n) {
          const int row = n * 16 + c;
          const int bir = (ks * 64 + g * 16) ^ ((row & 7) << 4);
          vf[n] = *(const bf16x8*)(vb + row * 128 + bir);
        }
#pragma unroll
        for (int m = 0; m < 2; ++m)
#pragma unroll
          for (int n = 0; n < 4; ++n)
            o[m][n] = __builtin_amdgcn_mfma_f32_16x16x32_bf16(pf[m], vf[n],
                                                              o[m][n], 0, 0, 0);
      }
      __builtin_amdgcn_s_setprio(0);
    }

    // finalize y = o/l, write merged [B*T][C] bf16
#pragma unroll
    for (int m = 0; m < 2; ++m)
#pragma unroll
      for (int j = 0; j < 4; ++j) {
        const float inv = 1.0f / lrow[m][j];
        const int qi = qbase + wid * 32 + m * 16 + g * 4 + j;
        const size_t rowoff = ((size_t)b * T_ + qi) * C_ + h * 64;
#pragma unroll
        for (int n = 0; n < 4; ++n)
          yatt[rowoff + n * 16 + c] = f2bf(o[m][n][j] * inv);
      }
  }
}

// ---------------- launch ----------------
extern "C" void kernel_launch(void* const* d_in, const int* in_sizes, int n_in,
                              void* d_out, int out_size, void* d_ws, size_t ws_size,
                              hipStream_t stream) {
  (void)in_sizes; (void)n_in; (void)out_size;
  const float* x      = (const float*)d_in[0];
  const float* pos    = (const float*)d_in[1];
  const float* w_attn = (const float*)d_in[2];
  const float* b_attn = (const float*)d_in[3];
  const float* w_proj = (const float*)d_in[4];
  const float* b_proj = (const float*)d_in[5];
  float* out = (float*)d_out;

  if (ws_size < (size_t)(88u << 20)) return;  // need 88MB scratch
  char* ws = (char*)d_ws;
  ushort* xbf  = (ushort*)(ws);                       // 16MB  x bf16 [8192][1024]
  ushort* waT  = (ushort*)(ws + (16 << 20));          // 6MB   w_attn^T bf16 [3072][1024]
  ushort* wpT  = (ushort*)(ws + (22 << 20));          // 2MB   w_proj^T bf16 [1024][1024]
  ushort* qbf  = (ushort*)(ws + (24 << 20));          // 16MB  q bf16 [BH][T][64] (pre-scaled)
  ushort* kbf  = (ushort*)(ws + (40 << 20));          // 16MB  k bf16 [BH][T][64]
  ushort* vtbf = (ushort*)(ws + (56 << 20));          // 16MB  v^T bf16 [BH][64][T]
  ushort* yatt = (ushort*)(ws + (72 << 20));          // 16MB  attn out bf16 [8192][1024]

  k_cvt<<<8192, 256, 0, stream>>>(x, xbf, 2097152);
  k_transpose_bf16<<<dim3(96, 32), 256, 0, stream>>>(w_attn, waT, 1024, 3072);
  k_transpose_bf16<<<dim3(32, 32), 256, 0, stream>>>(w_proj, wpT, 1024, 1024);
  k_gemm<0><<<dim3(64, 24), 256, 0, stream>>>(xbf, waT, b_attn, pos, out, qbf, kbf,
                                              vtbf, 8192, 3072, 1024);
  k_attn<<<dim3(8, 64), 256, 0, stream>>>(qbf, kbf, vtbf, yatt);
  k_gemm<1><<<dim3(64, 8), 256, 0, stream>>>(yatt, wpT, b_proj, nullptr, out, nullptr,
                                             nullptr, nullptr, 8192, 1024, 1024);
}

// Round 5
// 385.114 us; speedup vs baseline: 1.7197x; 1.1161x over previous
//
#include <hip/hip_runtime.h>
#include <hip/hip_bf16.h>
#include <stdint.h>

// B=4, T=2048, C=1024, H=16, HD=64
#define B_  4
#define T_  2048
#define C_  1024
#define H_  16
#define HD_ 64
#define YSZ 8388608  // B*T*C

typedef __attribute__((ext_vector_type(8))) __bf16 bf16x8;
typedef __attribute__((ext_vector_type(4))) float  f32x4;

__device__ __forceinline__ ushort f2bf(float x) {
  union { float f; uint32_t u; } v; v.f = x;
  uint32_t r = v.u + 0x7FFFu + ((v.u >> 16) & 1u);
  return (ushort)(r >> 16);
}

__device__ __forceinline__ uint32_t cvt_pk_bf16(float lo, float hi) {
  uint32_t r;
  asm("v_cvt_pk_bf16_f32 %0, %1, %2" : "=v"(r) : "v"(lo), "v"(hi));
  return r;
}

__device__ __forceinline__ void async16(void* lds, const void* g) {
  __builtin_amdgcn_global_load_lds(
      (const __attribute__((address_space(1))) void*)g,
      (__attribute__((address_space(3))) void*)lds, 16, 0, 0);
}

// ---------------- prep: fp32 -> bf16 (vectorized) ----------------
__global__ __launch_bounds__(256) void k_cvt(const float* __restrict__ in,
                                             ushort* __restrict__ out, int n4) {
  int i = blockIdx.x * 256 + threadIdx.x;
  if (i < n4) {
    const float4 v = ((const float4*)in)[i];
    ushort4 o; o.x = f2bf(v.x); o.y = f2bf(v.y); o.z = f2bf(v.z); o.w = f2bf(v.w);
    ((ushort4*)out)[i] = o;
  }
}

// ---------------- prep: transpose fp32 [rows][cols] -> bf16 [cols][rows] ----
__global__ __launch_bounds__(256) void k_transpose_bf16(const float* __restrict__ in,
                                                        ushort* __restrict__ out,
                                                        int rows, int cols) {
  __shared__ float tile[32][33];
  const int bx = blockIdx.x * 32;  // col base
  const int by = blockIdx.y * 32;  // row base
  const int tx = threadIdx.x & 31;
  const int ty = threadIdx.x >> 5;  // 0..7
#pragma unroll
  for (int j = 0; j < 4; ++j)
    tile[ty + j * 8][tx] = in[(size_t)(by + ty + j * 8) * cols + bx + tx];
  __syncthreads();
#pragma unroll
  for (int j = 0; j < 4; ++j)
    out[(size_t)(bx + ty + j * 8) * rows + by + tx] = f2bf(tile[tx][ty + j * 8]);
}

// ---------------- bf16 MFMA GEMM, 128x128 tile, BK=64 ----------------
// A [M][K] bf16 row-major, Bt [N][K] bf16 row-major (i.e. B transposed).
// MODE 0: QKV epilogue (bias + pos_emb, head-split, k/v fp32 out, q/k bf16, v^T bf16)
//         q is pre-scaled by 1/sqrt(HD)*log2(e) for the attn exp2 domain.
// MODE 1: proj epilogue (bias, fp32 y out)
template <int MODE>
__global__ __launch_bounds__(256) void k_gemm(
    const ushort* __restrict__ A, const ushort* __restrict__ Bt,
    const float* __restrict__ bias, const float* __restrict__ pos,
    float* __restrict__ outY, ushort* __restrict__ qbf, ushort* __restrict__ kbf,
    ushort* __restrict__ vtbf, int M, int N, int K) {
  __shared__ ushort Ab[128 * 64];
  __shared__ ushort Bb[128 * 64];
  const int tid = threadIdx.x;
  const int wid = tid >> 6, lane = tid & 63;
  const int wr = wid >> 1, wc = wid & 1;
  const int g = lane >> 4, c = lane & 15;
  const int bm = blockIdx.x * 128;
  const int bn = blockIdx.y * 128;

  f32x4 acc[4][4] = {};

  const int r0 = wid * 8 + (lane >> 3);  // row-in-round
  const int ch = lane & 7;               // 16B chunk within 128B row

  for (int kt = 0; kt < K; kt += 64) {
    __syncthreads();
#pragma unroll
    for (int rnd = 0; rnd < 4; ++rnd) {
      const int r = rnd * 32 + r0;
      const int gc = (ch ^ (r & 7)) << 3;  // pre-swizzled global col (elements)
      async16((char*)Ab + rnd * 4096 + wid * 1024,
              A + (size_t)(bm + r) * K + kt + gc);
      async16((char*)Bb + rnd * 4096 + wid * 1024,
              Bt + (size_t)(bn + r) * K + kt + gc);
    }
    __syncthreads();
#pragma unroll
    for (int ks = 0; ks < 2; ++ks) {
      bf16x8 af[4], bfr[4];
#pragma unroll
      for (int m = 0; m < 4; ++m) {
        const int row = wr * 64 + m * 16 + c;
        const int bir = (ks * 64 + g * 16) ^ ((row & 7) << 4);
        af[m] = *(const bf16x8*)((const char*)Ab + row * 128 + bir);
      }
#pragma unroll
      for (int n = 0; n < 4; ++n) {
        const int row = wc * 64 + n * 16 + c;
        const int bir = (ks * 64 + g * 16) ^ ((row & 7) << 4);
        bfr[n] = *(const bf16x8*)((const char*)Bb + row * 128 + bir);
      }
#pragma unroll
      for (int m = 0; m < 4; ++m)
#pragma unroll
        for (int n = 0; n < 4; ++n)
          acc[m][n] = __builtin_amdgcn_mfma_f32_16x16x32_bf16(af[m], bfr[n],
                                                              acc[m][n], 0, 0, 0);
    }
  }

  // epilogue: D row=(lane>>4)*4+j, col=lane&15 (measured layout)
  const float QSC = 0.125f * 1.4426950408889634f;  // 1/sqrt(64) * log2(e)
#pragma unroll
  for (int m = 0; m < 4; ++m) {
    const int rowbase = bm + wr * 64 + m * 16 + g * 4;
#pragma unroll
    for (int n = 0; n < 4; ++n) {
      const int col = bn + wc * 64 + n * 16 + c;
#pragma unroll
      for (int j = 0; j < 4; ++j) {
        const int i = rowbase + j;
        float val = acc[m][n][j] + bias[col];
        if (MODE == 1) {
          outY[(size_t)i * N + col] = val;
        } else {
          const int b = i >> 11, t = i & 2047;
          if (col < C_) {  // q (pre-scaled for attn)
            val += pos[t * C_ + col];
            const int h = col >> 6, hd = col & 63;
            const size_t o = (((size_t)(b * H_ + h)) * T_ + t) * HD_ + hd;
            qbf[o] = f2bf(val * QSC);
          } else if (col < 2 * C_) {  // k
            const int cc = col - C_;
            val += pos[t * C_ + cc];
            const int h = cc >> 6, hd = cc & 63;
            const size_t o = (((size_t)(b * H_ + h)) * T_ + t) * HD_ + hd;
            outY[(size_t)YSZ + o] = val;
            kbf[o] = f2bf(val);
          } else {  // v
            const int cc = col - 2 * C_;
            const int h = cc >> 6, hd = cc & 63;
            const size_t o = (((size_t)(b * H_ + h)) * T_ + t) * HD_ + hd;
            outY[(size_t)(2 * YSZ) + o] = val;
            vtbf[(((size_t)(b * H_ + h)) * HD_ + hd) * T_ + t] = f2bf(val);
          }
        }
      }
    }
  }
}

// ---------------- flash attention, swapped-operand bf16 MFMA ----------------
// q,k: [BH][T][64] bf16 (q pre-scaled) ; vT: [BH][64][T] bf16 ;
// yatt out: [B*T][C] bf16.
// S^T = mfma(K, Q): lane owns COLUMN q=m*16+c, rows kv=n*16+4g+j ->
// softmax reduce is 15 local fmax + 2 shuffles; P-write is cvt_pk pairs +
// ds_write_b64 of 4 consecutive kv. PV = mfma(V^T, P^T) = Y^T[d][q]; corr/l
// per-column = lane-local. Defer-max (THR=8, exp2 domain) skips rescale.
__global__ __launch_bounds__(256) void k_attn(const ushort* __restrict__ qbf,
                                              const ushort* __restrict__ kbf,
                                              const ushort* __restrict__ vtbf,
                                              ushort* __restrict__ yatt) {
  __shared__ ushort Kb[2][64 * 64];
  __shared__ ushort Vb[2][64 * 64];
  __shared__ ushort Pb[4][2048];  // per-wave 32x64 bf16, swizzled [q][kv]
  const int tid = threadIdx.x;
  const int wid = tid >> 6, lane = tid & 63;
  const int g = lane >> 4, c = lane & 15;
  const int bh = blockIdx.y;
  const size_t bhT = (size_t)bh * T_ * 64;
  const int r0 = wid * 8 + (lane >> 3);
  const int ch = lane & 7;
  const int b = bh >> 4, h = bh & 15;

  auto stage = [&](int buf, int t) {
    const int kv0 = t * 64;
#pragma unroll
    for (int rnd = 0; rnd < 2; ++rnd) {
      const int r = rnd * 32 + r0;
      const int gc = (ch ^ (r & 7)) << 3;
      async16((char*)Kb[buf] + rnd * 4096 + wid * 1024,
              kbf + bhT + (size_t)(kv0 + r) * 64 + gc);
      async16((char*)Vb[buf] + rnd * 4096 + wid * 1024,
              vtbf + bhT + (size_t)r * T_ + kv0 + gc);
    }
  };

  for (int half = 0; half < 2; ++half) {
    const int qtile = half ? (15 - (int)blockIdx.x) : (int)blockIdx.x;
    const int qbase = qtile * 128;
    const int ntiles = qtile * 2 + 2;
    const int qmin = qbase + wid * 32;
    const int qcol0 = qbase + wid * 32 + c;  // this lane's q for m=0 (m adds 16)

    // Q fragments (B-operand: col=q=m*16+c, k=d=ks*32+g*8+j) — same bytes as before
    bf16x8 qf[2][2];
#pragma unroll
    for (int m = 0; m < 2; ++m)
#pragma unroll
      for (int ks = 0; ks < 2; ++ks)
        qf[m][ks] = *(const bf16x8*)(qbf + bhT +
                                     (size_t)(qbase + wid * 32 + m * 16 + c) * 64 +
                                     ks * 32 + g * 8);

    f32x4 o2[4][2] = {};        // Y^T: [n' over d][m over q]
    float mrow[2], lrow[2];
#pragma unroll
    for (int m = 0; m < 2; ++m) { mrow[m] = -__builtin_inff(); lrow[m] = 0.f; }

    for (int t = 0; t < ntiles; ++t) {
      if (t == 0) {            // prologue: wait for prior readers, stage tile 0
        __syncthreads();
        stage(0, 0);
      }
      __syncthreads();         // compiler drains vmcnt -> buf[t&1] ready
      if (t + 1 < ntiles) stage((t + 1) & 1, t + 1);  // prefetch under compute

      const char* kb = (const char*)Kb[t & 1];
      const char* vb = (const char*)Vb[t & 1];
      const int kv0 = t * 64;

      // S^T = K Q^T : s2[n][m], lane holds col q=m*16+c, rows kv=n*16+4g+j
      f32x4 s2[4][2] = {};
      __builtin_amdgcn_s_setprio(1);
#pragma unroll
      for (int ks = 0; ks < 2; ++ks) {
        bf16x8 kf[4];
#pragma unroll
        for (int n = 0; n < 4; ++n) {
          const int row = n * 16 + c;
          const int bir = (ks * 64 + g * 16) ^ ((row & 7) << 4);
          kf[n] = *(const bf16x8*)(kb + row * 128 + bir);
        }
#pragma unroll
        for (int n = 0; n < 4; ++n)
#pragma unroll
          for (int m = 0; m < 2; ++m)
            s2[n][m] = __builtin_amdgcn_mfma_f32_16x16x32_bf16(kf[n], qf[m][ks],
                                                               s2[n][m], 0, 0, 0);
      }
      __builtin_amdgcn_s_setprio(0);

      // causal mask
      if (kv0 + 63 > qmin) {
#pragma unroll
        for (int n = 0; n < 4; ++n)
#pragma unroll
          for (int j = 0; j < 4; ++j) {
            const int kvi = kv0 + n * 16 + 4 * g + j;
#pragma unroll
            for (int m = 0; m < 2; ++m)
              if (kvi > qcol0 + m * 16) s2[n][m][j] = -__builtin_inff();
          }
      }

      // online softmax per column q (lane-local row; 2 shuffles to merge g-groups)
#pragma unroll
      for (int m = 0; m < 2; ++m) {
        float pmax = s2[0][m][0];
#pragma unroll
        for (int n = 0; n < 4; ++n)
#pragma unroll
          for (int j = 0; j < 4; ++j) pmax = fmaxf(pmax, s2[n][m][j]);
        pmax = fmaxf(pmax, __shfl_xor(pmax, 16));
        pmax = fmaxf(pmax, __shfl_xor(pmax, 32));
        const bool skip = __all(pmax - mrow[m] <= 8.0f);  // defer-max (T13)
        const float mnew = skip ? mrow[m] : pmax;
        float rs = 0.f;
#pragma unroll
        for (int n = 0; n < 4; ++n)
#pragma unroll
          for (int j = 0; j < 4; ++j) {
            const float pv = exp2f(s2[n][m][j] - mnew);
            s2[n][m][j] = pv;
            rs += pv;
          }
        rs += __shfl_xor(rs, 16);
        rs += __shfl_xor(rs, 32);
        if (skip) {
          lrow[m] += rs;
        } else {
          const float corr = exp2f(mrow[m] - pmax);
          lrow[m] = lrow[m] * corr + rs;
          mrow[m] = pmax;
#pragma unroll
          for (int n2 = 0; n2 < 4; ++n2)
#pragma unroll
            for (int j = 0; j < 4; ++j) o2[n2][m][j] *= corr;
        }
      }

      // P -> per-wave LDS: 4 consecutive kv per (m,n) -> 2 cvt_pk + 1 b64 write
      asm volatile("" ::: "memory");
      char* pb = (char*)&Pb[wid][0];
#pragma unroll
      for (int m = 0; m < 2; ++m) {
        const int q = m * 16 + c;
#pragma unroll
        for (int n = 0; n < 4; ++n) {
          const uint32_t w0 = cvt_pk_bf16(s2[n][m][0], s2[n][m][1]);
          const uint32_t w1 = cvt_pk_bf16(s2[n][m][2], s2[n][m][3]);
          const int kvl = n * 16 + 4 * g;
          const int byte = q * 128 + ((kvl * 2) ^ ((q & 7) << 4));
          *(uint2*)(pb + byte) = make_uint2(w0, w1);
        }
      }
      asm volatile("" ::: "memory");

      // PV (swapped): o2 = mfma(V^T, P^T) -> Y^T[d][q]
      __builtin_amdgcn_s_setprio(1);
#pragma unroll
      for (int ks = 0; ks < 2; ++ks) {
        bf16x8 pf[2], vf[4];
#pragma unroll
        for (int m = 0; m < 2; ++m) {
          const int row = m * 16 + c;
          const int bir = (ks * 64 + g * 16) ^ ((row & 7) << 4);
          pf[m] = *(const bf16x8*)(pb + row * 128 + bir);
        }
#pragma unroll
        for (int n = 0; n < 4; ++n) {
          const int row = n * 16 + c;
          const int bir = (ks * 64 + g * 16) ^ ((row & 7) << 4);
          vf[n] = *(const bf16x8*)(vb + row * 128 + bir);
        }
#pragma unroll
        for (int n = 0; n < 4; ++n)
#pragma unroll
          for (int m = 0; m < 2; ++m)
            o2[n][m] = __builtin_amdgcn_mfma_f32_16x16x32_bf16(vf[n], pf[m],
                                                               o2[n][m], 0, 0, 0);
      }
      __builtin_amdgcn_s_setprio(0);
    }

    // finalize y = o/l; lane holds column q, d = n'*16+4g+j (scattered store)
#pragma unroll
    for (int m = 0; m < 2; ++m) {
      const float inv = 1.0f / lrow[m];
      const int qi = qbase + wid * 32 + m * 16 + c;
      const size_t rowoff = ((size_t)b * T_ + qi) * C_ + h * 64;
#pragma unroll
      for (int n = 0; n < 4; ++n)
#pragma unroll
        for (int j = 0; j < 4; ++j)
          yatt[rowoff + n * 16 + 4 * g + j] = f2bf(o2[n][m][j] * inv);
    }
  }
}

// ---------------- launch ----------------
extern "C" void kernel_launch(void* const* d_in, const int* in_sizes, int n_in,
                              void* d_out, int out_size, void* d_ws, size_t ws_size,
                              hipStream_t stream) {
  (void)in_sizes; (void)n_in; (void)out_size;
  const float* x      = (const float*)d_in[0];
  const float* pos    = (const float*)d_in[1];
  const float* w_attn = (const float*)d_in[2];
  const float* b_attn = (const float*)d_in[3];
  const float* w_proj = (const float*)d_in[4];
  const float* b_proj = (const float*)d_in[5];
  float* out = (float*)d_out;

  if (ws_size < (size_t)(88u << 20)) return;  // need 88MB scratch
  char* ws = (char*)d_ws;
  ushort* xbf  = (ushort*)(ws);                       // 16MB  x bf16 [8192][1024]
  ushort* waT  = (ushort*)(ws + (16 << 20));          // 6MB   w_attn^T bf16 [3072][1024]
  ushort* wpT  = (ushort*)(ws + (22 << 20));          // 2MB   w_proj^T bf16 [1024][1024]
  ushort* qbf  = (ushort*)(ws + (24 << 20));          // 16MB  q bf16 [BH][T][64] (pre-scaled)
  ushort* kbf  = (ushort*)(ws + (40 << 20));          // 16MB  k bf16 [BH][T][64]
  ushort* vtbf = (ushort*)(ws + (56 << 20));          // 16MB  v^T bf16 [BH][64][T]
  ushort* yatt = (ushort*)(ws + (72 << 20));          // 16MB  attn out bf16 [8192][1024]

  k_cvt<<<8192, 256, 0, stream>>>(x, xbf, 2097152);
  k_transpose_bf16<<<dim3(96, 32), 256, 0, stream>>>(w_attn, waT, 1024, 3072);
  k_transpose_bf16<<<dim3(32, 32), 256, 0, stream>>>(w_proj, wpT, 1024, 1024);
  k_gemm<0><<<dim3(64, 24), 256, 0, stream>>>(xbf, waT, b_attn, pos, out, qbf, kbf,
                                              vtbf, 8192, 3072, 1024);
  k_attn<<<dim3(8, 64), 256, 0, stream>>>(qbf, kbf, vtbf, yatt);
  k_gemm<1><<<dim3(64, 8), 256, 0, stream>>>(yatt, wpT, b_proj, nullptr, out, nullptr,
                                             nullptr, nullptr, 8192, 1024, 1024);
}